// Round 14
// baseline (70.992 us; speedup 1.0000x reference)
//
#include <hip/hip_runtime.h>
#include <cstddef>

typedef __attribute__((ext_vector_type(8))) short short8;
typedef __attribute__((ext_vector_type(16))) float f32x16;

#define NB 4
#define NSEQ 6400
#define CDIM 48
#define DHEAD 16
#define WSZ 800
#define NWIN 8
#define INNER 64
#define NROWS 25600
#define NWH 256                       // 2*NB*NWIN*NHEADS window-heads
#define SCHUNK (WSZ * DHEAD)          // 12800
#define CHUNK (3 * SCHUNK)            // 38400 bf16 per (e,b,w,h)
#define QKV_TOTAL (NWH * CHUNK)
#define AO_PER (NROWS * INNER)        // bf16 elements per input

static __device__ __forceinline__ uint pkbf(float a, float b) {
  uint r;
  asm("v_cvt_pk_bf16_f32 %0, %1, %2" : "=v"(r) : "v"(a), "v"(b));
  return r;
}
static __device__ __forceinline__ float bf2f(ushort u) {
  return __uint_as_float(((uint)u) << 16);
}

// ---------------------------------------------------------------------------
// Kernel 1: QKV projection via MFMA (exact r12 version; Q pre-scaled 0.25).
// ---------------------------------------------------------------------------
__global__ __launch_bounds__(256) void qkv_mfma(const float* __restrict__ x1,
                                                const float* __restrict__ x2,
                                                const float* __restrict__ Wqkv,
                                                ushort* __restrict__ wsq) {
  const int tid = threadIdx.x;
  const int lane = tid & 63;
  const int wv = tid >> 6;

  __shared__ __align__(16) ushort Wl[18 * 64 * 8];   // 18.4 KB, frag order
  __shared__ __align__(16) ushort Obuf[4][6 * 512];  // 6KB per wave

  for (int slot = tid; slot < 1152; slot += 256) {
    const int mtks = slot >> 6, l2 = slot & 63;
    const int mt = mtks / 3, ks = mtks % 3;
    const int o = mt * 32 + (l2 & 31);
    const int c0 = ks * 16 + (l2 >> 5) * 8;
    const float sc = ((o % CDIM) < DHEAD) ? 0.25f : 1.0f;   // fold attn scale
    const float4* p = reinterpret_cast<const float4*>(Wqkv + (size_t)o * CDIM + c0);
    float4 u = p[0], v = p[1];
    union { uint q[4]; short8 s; } t;
    t.q[0] = pkbf(u.x * sc, u.y * sc); t.q[1] = pkbf(u.z * sc, u.w * sc);
    t.q[2] = pkbf(v.x * sc, v.y * sc); t.q[3] = pkbf(v.z * sc, v.w * sc);
    *reinterpret_cast<short8*>(Wl + (size_t)slot * 8) = t.s;
  }
  __syncthreads();

  const int task = blockIdx.x * 4 + wv;   // [0,3200)
  const int batch = task >> 1;
  const int mh = task & 1;
  const int e = batch / 800;
  const int rb = (batch % 800) * 32;
  const float* __restrict__ x = e ? x2 : x1;

  const int rl = lane & 31;
  const int lg = lane >> 5;
  const int row = rb + rl;

  short8 bf[3];
#pragma unroll
  for (int ks = 0; ks < 3; ++ks) {
    const float4* p =
        reinterpret_cast<const float4*>(x + (size_t)row * CDIM + ks * 16 + lg * 8);
    float4 u = p[0], v = p[1];
    union { uint q[4]; short8 s; } t;
    t.q[0] = pkbf(u.x, u.y); t.q[1] = pkbf(u.z, u.w);
    t.q[2] = pkbf(v.x, v.y); t.q[3] = pkbf(v.z, v.w);
    bf[ks] = t.s;
  }

  const int b = rb / NSEQ;
  const int i0 = rb % NSEQ;
  const int wi = i0 / WSZ;
  const int iwb = i0 % WSZ;
  const int whb = ((e * NB + b) * NWIN + wi) * 4;

#pragma unroll
  for (int mt = mh * 3; mt < mh * 3 + 3; ++mt) {
    const int obase = mt * 32;
    short8 wf0 = *reinterpret_cast<const short8*>(Wl + ((mt * 3 + 0) * 64 + lane) * 8);
    short8 wf1 = *reinterpret_cast<const short8*>(Wl + ((mt * 3 + 1) * 64 + lane) * 8);
    short8 wf2 = *reinterpret_cast<const short8*>(Wl + ((mt * 3 + 2) * 64 + lane) * 8);

    f32x16 acc;
#pragma unroll
    for (int r = 0; r < 16; ++r) acc[r] = 0.f;
    acc = __builtin_amdgcn_mfma_f32_32x32x16_bf16(wf0, bf[0], acc, 0, 0, 0);
    acc = __builtin_amdgcn_mfma_f32_32x32x16_bf16(wf1, bf[1], acc, 0, 0, 0);
    acc = __builtin_amdgcn_mfma_f32_32x32x16_bf16(wf2, bf[2], acc, 0, 0, 0);

#pragma unroll
    for (int q = 0; q < 4; ++q) {
      const int op = obase + q * 8 + 4 * lg - mh * 96;   // 0..95
      const int g2 = op >> 4;
      const int d0 = op & 15;
      uint2 pk;
      pk.x = pkbf(acc[4 * q + 0], acc[4 * q + 1]);
      pk.y = pkbf(acc[4 * q + 2], acc[4 * q + 3]);
      *reinterpret_cast<uint2*>(&Obuf[wv][g2 * 512 + rl * 16 + d0]) = pk;
    }
  }

#pragma unroll
  for (int g2 = 0; g2 < 6; ++g2) {
    const int g = mh * 6 + g2;
    const int h = g / 3, s = g % 3;
    short8 val = *reinterpret_cast<const short8*>(&Obuf[wv][g2 * 512 + lane * 8]);
    *reinterpret_cast<short8*>(wsq + (size_t)(whb + h) * CHUNK + s * SCHUNK +
                               (size_t)iwb * DHEAD + lane * 8) = val;
  }
}

// ---------------------------------------------------------------------------
// Kernel 2: MFMA windowed attention — exact r12 structure (__expf, C-init -8,
// chunked V double-buffer) + ONE change: the chunk's 5 K A-frags are batch-
// loaded into registers before the jl loop (one vmcnt amortized per chunk
// instead of an L2-latency stall per jt).
// ---------------------------------------------------------------------------
#define JC 160
#define NCH 5
#define VROW 168
#define VSL (17 * VROW)

__global__ __launch_bounds__(320) void attn_mfma(const ushort* __restrict__ wsq,
                                                 ushort* __restrict__ ao) {
  const int tid = threadIdx.x;
  const int lane = tid & 63;
  const int wv = tid >> 6;
  const int bid = blockIdx.x;
  const int wh = bid & (NWH - 1);
  const int sub = bid >> 8;
  const int qtile = sub * 5 + wv;        // 0..24

  const ushort* __restrict__ Qg = wsq + (size_t)wh * CHUNK;
  const ushort* __restrict__ Kg = Qg + SCHUNK;
  const ushort* __restrict__ Vg = Kg + SCHUNK;

  __shared__ __align__(16) ushort Vs[2][VSL];   // 11.4 KB total

  const int vj = tid % 160;
  const int vhalf = tid / 160;

  short8 vreg = *reinterpret_cast<const short8*>(Vg + (size_t)vj * DHEAD + vhalf * 8);

  if (tid < JC) {
    Vs[0][16 * VROW + tid] = 0x3F80;
    Vs[1][16 * VROW + tid] = 0x3F80;
  }

#pragma unroll
  for (int u = 0; u < 8; ++u)
    Vs[0][(vhalf * 8 + u) * VROW + vj] = (ushort)vreg[u];

  vreg = *reinterpret_cast<const short8*>(Vg + (size_t)(JC + vj) * DHEAD + vhalf * 8);

  short8 qf = *reinterpret_cast<const short8*>(
      Qg + (size_t)(qtile * 32 + (lane & 31)) * DHEAD + (lane >> 5) * 8);

  __syncthreads();

  f32x16 sinit;
#pragma unroll
  for (int r = 0; r < 16; ++r) sinit[r] = -8.0f;   // softmax shift via C-in
  f32x16 accO;
#pragma unroll
  for (int r = 0; r < 16; ++r) accO[r] = 0.f;

  const int n31 = lane & 31;
  const int lg = lane >> 5;
  const int vrow = (n31 <= 16) ? n31 : (n31 & 15);   // col 16 -> ones row
  const ushort* __restrict__ kfb = Kg + (size_t)n31 * DHEAD + lg * 8;

  for (int ch = 0; ch < NCH; ++ch) {
    const ushort* __restrict__ Vc = Vs[ch & 1];

    // batch the chunk's 5 K A-frags into regs (coalesced 1KB/wave each)
    short8 kfs[5];
#pragma unroll
    for (int jl = 0; jl < 5; ++jl)
      kfs[jl] = *reinterpret_cast<const short8*>(
          kfb + (size_t)(ch * JC + jl * 32) * DHEAD);

#pragma unroll
    for (int jl = 0; jl < 5; ++jl) {
      f32x16 st = __builtin_amdgcn_mfma_f32_32x32x16_bf16(kfs[jl], qf, sinit, 0, 0, 0);

      float p[16];
#pragma unroll
      for (int r = 0; r < 16; ++r) p[r] = __expf(st[r]);   // exp(s-8)

      uint x0, x1, y0, y1;
      asm("v_cvt_pk_bf16_f32 %0, %1, %2" : "=v"(x0) : "v"(p[0]), "v"(p[1]));
      asm("v_cvt_pk_bf16_f32 %0, %1, %2" : "=v"(x1) : "v"(p[2]), "v"(p[3]));
      asm("v_cvt_pk_bf16_f32 %0, %1, %2" : "=v"(y0) : "v"(p[4]), "v"(p[5]));
      asm("v_cvt_pk_bf16_f32 %0, %1, %2" : "=v"(y1) : "v"(p[6]), "v"(p[7]));
      asm("v_permlane32_swap_b32 %0, %1" : "+v"(x0), "+v"(y0));
      asm("v_permlane32_swap_b32 %0, %1" : "+v"(x1), "+v"(y1));
      union { uint u[4]; short8 s; } pa0;
      pa0.u[0] = x0; pa0.u[1] = x1; pa0.u[2] = y0; pa0.u[3] = y1;

      uint z0, z1, w0, w1;
      asm("v_cvt_pk_bf16_f32 %0, %1, %2" : "=v"(z0) : "v"(p[8]), "v"(p[9]));
      asm("v_cvt_pk_bf16_f32 %0, %1, %2" : "=v"(z1) : "v"(p[10]), "v"(p[11]));
      asm("v_cvt_pk_bf16_f32 %0, %1, %2" : "=v"(w0) : "v"(p[12]), "v"(p[13]));
      asm("v_cvt_pk_bf16_f32 %0, %1, %2" : "=v"(w1) : "v"(p[14]), "v"(p[15]));
      asm("v_permlane32_swap_b32 %0, %1" : "+v"(z0), "+v"(w0));
      asm("v_permlane32_swap_b32 %0, %1" : "+v"(z1), "+v"(w1));
      union { uint u[4]; short8 s; } pa1;
      pa1.u[0] = z0; pa1.u[1] = z1; pa1.u[2] = w0; pa1.u[3] = w1;

      short8 vf0 = *reinterpret_cast<const short8*>(Vc + vrow * VROW + jl * 32 + lg * 8);
      short8 vf1 = *reinterpret_cast<const short8*>(Vc + vrow * VROW + jl * 32 + 16 + lg * 8);

      accO = __builtin_amdgcn_mfma_f32_32x32x16_bf16(pa0.s, vf0, accO, 0, 0, 0);
      accO = __builtin_amdgcn_mfma_f32_32x32x16_bf16(pa1.s, vf1, accO, 0, 0, 0);
    }
    if (ch + 1 < NCH) {
      __syncthreads();
      const int nxt = (ch + 1) & 1;
#pragma unroll
      for (int u = 0; u < 8; ++u)
        Vs[nxt][(vhalf * 8 + u) * VROW + vj] = (ushort)vreg[u];
      if (ch + 2 < NCH) {
        vreg = *reinterpret_cast<const short8*>(
            Vg + (size_t)((ch + 2) * JC + vj) * DHEAD + vhalf * 8);
      }
      __syncthreads();
    }
  }

  const int h = wh & 3;
  const int w = (wh >> 2) & 7;
  const int b = (wh >> 5) & 3;
  const int e = wh >> 7;
  const size_t rowbase =
      (size_t)e * NROWS + (size_t)b * NSEQ + (size_t)w * WSZ + (size_t)qtile * 32;
  const int src = 16 + 32 * lg;

#pragma unroll
  for (int r = 0; r < 16; ++r) {
    float den = __shfl(accO[r], src);
    if (n31 < 16) {
      int i = (r & 3) + 8 * (r >> 2) + 4 * lg;
      float val = accO[r] * __builtin_amdgcn_rcpf(den);
      ao[(rowbase + i) * INNER + h * DHEAD + n31] = (ushort)pkbf(val, val);
    }
  }
}

// ---------------------------------------------------------------------------
// Kernel 3: out = (ao1 + ao2) @ Wout^T + 2*bout (exact r12 version).
// ---------------------------------------------------------------------------
#define OSTR 76
__global__ __launch_bounds__(192) void out_proj(const ushort* __restrict__ ao_all,
                                                const float* __restrict__ Wout,
                                                const float* __restrict__ bout,
                                                float* __restrict__ out) {
  const int tid = threadIdx.x;
  const int row0 = blockIdx.x * 64;

  __shared__ float aos[64 * OSTR];

  const ushort* __restrict__ a1 = ao_all;
  const ushort* __restrict__ a2 = ao_all + (size_t)AO_PER;

  for (int idx = tid; idx < 64 * 8; idx += 192) {
    const int r = idx >> 3, c = idx & 7;
    const size_t g = (size_t)(row0 + r) * INNER + c * 8;
    short8 u = *reinterpret_cast<const short8*>(a1 + g);
    short8 v = *reinterpret_cast<const short8*>(a2 + g);
    float4 s0, s1;
    s0.x = bf2f((ushort)u[0]) + bf2f((ushort)v[0]);
    s0.y = bf2f((ushort)u[1]) + bf2f((ushort)v[1]);
    s0.z = bf2f((ushort)u[2]) + bf2f((ushort)v[2]);
    s0.w = bf2f((ushort)u[3]) + bf2f((ushort)v[3]);
    s1.x = bf2f((ushort)u[4]) + bf2f((ushort)v[4]);
    s1.y = bf2f((ushort)u[5]) + bf2f((ushort)v[5]);
    s1.z = bf2f((ushort)u[6]) + bf2f((ushort)v[6]);
    s1.w = bf2f((ushort)u[7]) + bf2f((ushort)v[7]);
    *reinterpret_cast<float4*>(aos + r * OSTR + c * 8) = s0;
    *reinterpret_cast<float4*>(aos + r * OSTR + c * 8 + 4) = s1;
  }

  const int j = tid % 48;
  const int rq = tid / 48;

  float wreg[INNER];
#pragma unroll
  for (int k4 = 0; k4 < 16; ++k4) {
    float4 wv4 = reinterpret_cast<const float4*>(Wout + (size_t)j * INNER)[k4];
    wreg[k4 * 4 + 0] = wv4.x; wreg[k4 * 4 + 1] = wv4.y;
    wreg[k4 * 4 + 2] = wv4.z; wreg[k4 * 4 + 3] = wv4.w;
  }
  const float bj = 2.0f * bout[j];

  __syncthreads();

  for (int r16 = 0; r16 < 16; ++r16) {
    const int r = rq * 16 + r16;
    float a0 = 0.f, a1v = 0.f, a2v = 0.f, a3 = 0.f;
#pragma unroll
    for (int kk = 0; kk < 16; ++kk) {
      const int k4 = (kk + rq * 4) & 15;
      float4 av = *reinterpret_cast<const float4*>(aos + r * OSTR + k4 * 4);
      a0 = fmaf(av.x, wreg[k4 * 4 + 0], a0);
      a1v = fmaf(av.y, wreg[k4 * 4 + 1], a1v);
      a2v = fmaf(av.z, wreg[k4 * 4 + 2], a2v);
      a3 = fmaf(av.w, wreg[k4 * 4 + 3], a3);
    }
    out[(size_t)(row0 + r) * CDIM + j] = (a0 + a1v) + (a2v + a3) + bj;
  }
}

// ---------------------------------------------------------------------------
extern "C" void kernel_launch(void* const* d_in, const int* in_sizes, int n_in,
                              void* d_out, int out_size, void* d_ws,
                              size_t ws_size, hipStream_t stream) {
  const float* x1 = (const float*)d_in[0];
  const float* x2 = (const float*)d_in[1];
  const float* Wqkv = (const float*)d_in[2];
  const float* Wout = (const float*)d_in[3];
  const float* bout = (const float*)d_in[4];
  float* out = (float*)d_out;
  ushort* wsq = (ushort*)d_ws;
  ushort* ao = wsq + QKV_TOTAL;          // bf16 region after bf16 QKV

  qkv_mfma<<<dim3(800), dim3(256), 0, stream>>>(x1, x2, Wqkv, wsq);
  attn_mfma<<<dim3(1280), dim3(320), 0, stream>>>(wsq, ao);
  out_proj<<<dim3(400), dim3(192), 0, stream>>>(ao, Wout, bout, out);
}

// Round 16
// 65.910 us; speedup vs baseline: 1.0771x; 1.0771x over previous
//
#include <hip/hip_runtime.h>
#include <cstddef>

typedef __attribute__((ext_vector_type(8))) short short8;
typedef __attribute__((ext_vector_type(16))) float f32x16;

#define NB 4
#define NSEQ 6400
#define CDIM 48
#define DHEAD 16
#define WSZ 800
#define NWIN 8
#define INNER 64
#define NROWS 25600
#define NWH 256                       // 2*NB*NWIN*NHEADS window-heads
#define SCHUNK (WSZ * DHEAD)          // 12800
#define CHUNK (3 * SCHUNK)            // 38400 bf16 per (e,b,w,h)
#define QKV_TOTAL (NWH * CHUNK)
#define AO_PER (NROWS * INNER)        // bf16 elements per input

static __device__ __forceinline__ uint pkbf(float a, float b) {
  uint r;
  asm("v_cvt_pk_bf16_f32 %0, %1, %2" : "=v"(r) : "v"(a), "v"(b));
  return r;
}
static __device__ __forceinline__ float bf2f(ushort u) {
  return __uint_as_float(((uint)u) << 16);
}

// ---------------------------------------------------------------------------
// Kernel 1: QKV projection via MFMA, C^T formulation (LDS W frags +
// wave-private Obuf staging -> 6 coalesced 1KB stores).  Q pre-scaled 0.25.
// ---------------------------------------------------------------------------
__global__ __launch_bounds__(256) void qkv_mfma(const float* __restrict__ x1,
                                                const float* __restrict__ x2,
                                                const float* __restrict__ Wqkv,
                                                ushort* __restrict__ wsq) {
  const int tid = threadIdx.x;
  const int lane = tid & 63;
  const int wv = tid >> 6;

  __shared__ __align__(16) ushort Wl[18 * 64 * 8];   // 18.4 KB, frag order
  __shared__ __align__(16) ushort Obuf[4][6 * 512];  // 6KB per wave

  for (int slot = tid; slot < 1152; slot += 256) {
    const int mtks = slot >> 6, l2 = slot & 63;
    const int mt = mtks / 3, ks = mtks % 3;
    const int o = mt * 32 + (l2 & 31);
    const int c0 = ks * 16 + (l2 >> 5) * 8;
    const float sc = ((o % CDIM) < DHEAD) ? 0.25f : 1.0f;   // fold attn scale
    const float4* p = reinterpret_cast<const float4*>(Wqkv + (size_t)o * CDIM + c0);
    float4 u = p[0], v = p[1];
    union { uint q[4]; short8 s; } t;
    t.q[0] = pkbf(u.x * sc, u.y * sc); t.q[1] = pkbf(u.z * sc, u.w * sc);
    t.q[2] = pkbf(v.x * sc, v.y * sc); t.q[3] = pkbf(v.z * sc, v.w * sc);
    *reinterpret_cast<short8*>(Wl + (size_t)slot * 8) = t.s;
  }
  __syncthreads();

  const int task = blockIdx.x * 4 + wv;   // [0,3200)
  const int batch = task >> 1;
  const int mh = task & 1;
  const int e = batch / 800;
  const int rb = (batch % 800) * 32;
  const float* __restrict__ x = e ? x2 : x1;

  const int rl = lane & 31;
  const int lg = lane >> 5;
  const int row = rb + rl;

  short8 bf[3];
#pragma unroll
  for (int ks = 0; ks < 3; ++ks) {
    const float4* p =
        reinterpret_cast<const float4*>(x + (size_t)row * CDIM + ks * 16 + lg * 8);
    float4 u = p[0], v = p[1];
    union { uint q[4]; short8 s; } t;
    t.q[0] = pkbf(u.x, u.y); t.q[1] = pkbf(u.z, u.w);
    t.q[2] = pkbf(v.x, v.y); t.q[3] = pkbf(v.z, v.w);
    bf[ks] = t.s;
  }

  const int b = rb / NSEQ;
  const int i0 = rb % NSEQ;
  const int wi = i0 / WSZ;
  const int iwb = i0 % WSZ;
  const int whb = ((e * NB + b) * NWIN + wi) * 4;

#pragma unroll
  for (int mt = mh * 3; mt < mh * 3 + 3; ++mt) {
    const int obase = mt * 32;
    short8 wf0 = *reinterpret_cast<const short8*>(Wl + ((mt * 3 + 0) * 64 + lane) * 8);
    short8 wf1 = *reinterpret_cast<const short8*>(Wl + ((mt * 3 + 1) * 64 + lane) * 8);
    short8 wf2 = *reinterpret_cast<const short8*>(Wl + ((mt * 3 + 2) * 64 + lane) * 8);

    f32x16 acc;
#pragma unroll
    for (int r = 0; r < 16; ++r) acc[r] = 0.f;
    acc = __builtin_amdgcn_mfma_f32_32x32x16_bf16(wf0, bf[0], acc, 0, 0, 0);
    acc = __builtin_amdgcn_mfma_f32_32x32x16_bf16(wf1, bf[1], acc, 0, 0, 0);
    acc = __builtin_amdgcn_mfma_f32_32x32x16_bf16(wf2, bf[2], acc, 0, 0, 0);

#pragma unroll
    for (int q = 0; q < 4; ++q) {
      const int op = obase + q * 8 + 4 * lg - mh * 96;   // 0..95
      const int g2 = op >> 4;
      const int d0 = op & 15;
      uint2 pk;
      pk.x = pkbf(acc[4 * q + 0], acc[4 * q + 1]);
      pk.y = pkbf(acc[4 * q + 2], acc[4 * q + 3]);
      *reinterpret_cast<uint2*>(&Obuf[wv][g2 * 512 + rl * 16 + d0]) = pk;
    }
  }

#pragma unroll
  for (int g2 = 0; g2 < 6; ++g2) {
    const int g = mh * 6 + g2;           // global 16-o group
    const int h = g / 3, s = g % 3;
    short8 val = *reinterpret_cast<const short8*>(&Obuf[wv][g2 * 512 + lane * 8]);
    *reinterpret_cast<short8*>(wsq + (size_t)(whb + h) * CHUNK + s * SCHUNK +
                               (size_t)iwb * DHEAD + lane * 8) = val;
  }
}

// ---------------------------------------------------------------------------
// Kernel 2: MFMA windowed attention — champion r12 version, verbatim.
// K-frags direct from global (coalesced 1KB/wave/jt, L2-hot); chunked
// double-buffered V^T LDS staging with barriers; __expf softmax with the
// -8 shift folded into the MFMA C-init; ones-column denominator; V-frag
// reads AFTER the pack block (hoisting them breaks codegen — r9/r10/r15).
// ---------------------------------------------------------------------------
#define JC 160
#define NCH 5
#define VROW 168
#define VSL (17 * VROW)

__global__ __launch_bounds__(320) void attn_mfma(const ushort* __restrict__ wsq,
                                                 ushort* __restrict__ ao) {
  const int tid = threadIdx.x;
  const int lane = tid & 63;
  const int wv = tid >> 6;
  const int bid = blockIdx.x;
  const int wh = bid & (NWH - 1);
  const int sub = bid >> 8;
  const int qtile = sub * 5 + wv;        // 0..24

  const ushort* __restrict__ Qg = wsq + (size_t)wh * CHUNK;
  const ushort* __restrict__ Kg = Qg + SCHUNK;
  const ushort* __restrict__ Vg = Kg + SCHUNK;

  __shared__ __align__(16) ushort Vs[2][VSL];   // 11.4 KB total

  const int vj = tid % 160;
  const int vhalf = tid / 160;

  short8 vreg = *reinterpret_cast<const short8*>(Vg + (size_t)vj * DHEAD + vhalf * 8);

  if (tid < JC) {
    Vs[0][16 * VROW + tid] = 0x3F80;
    Vs[1][16 * VROW + tid] = 0x3F80;
  }

#pragma unroll
  for (int u = 0; u < 8; ++u)
    Vs[0][(vhalf * 8 + u) * VROW + vj] = (ushort)vreg[u];

  vreg = *reinterpret_cast<const short8*>(Vg + (size_t)(JC + vj) * DHEAD + vhalf * 8);

  short8 qf = *reinterpret_cast<const short8*>(
      Qg + (size_t)(qtile * 32 + (lane & 31)) * DHEAD + (lane >> 5) * 8);

  __syncthreads();

  f32x16 sinit;
#pragma unroll
  for (int r = 0; r < 16; ++r) sinit[r] = -8.0f;   // softmax shift via C-in
  f32x16 accO;
#pragma unroll
  for (int r = 0; r < 16; ++r) accO[r] = 0.f;

  const int n31 = lane & 31;
  const int lg = lane >> 5;
  const int vrow = (n31 <= 16) ? n31 : (n31 & 15);   // col 16 -> ones row
  const ushort* __restrict__ kfb = Kg + (size_t)n31 * DHEAD + lg * 8;

  for (int ch = 0; ch < NCH; ++ch) {
    const ushort* __restrict__ Vc = Vs[ch & 1];
#pragma unroll
    for (int jl = 0; jl < 5; ++jl) {
      // K A-frag direct from global: coalesced 1KB per wave, L2-hot
      short8 kf = *reinterpret_cast<const short8*>(
          kfb + (size_t)(ch * JC + jl * 32) * DHEAD);
      f32x16 st = __builtin_amdgcn_mfma_f32_32x32x16_bf16(kf, qf, sinit, 0, 0, 0);

      float p[16];
#pragma unroll
      for (int r = 0; r < 16; ++r) p[r] = __expf(st[r]);   // exp(s-8)

      uint x0, x1, y0, y1;
      asm("v_cvt_pk_bf16_f32 %0, %1, %2" : "=v"(x0) : "v"(p[0]), "v"(p[1]));
      asm("v_cvt_pk_bf16_f32 %0, %1, %2" : "=v"(x1) : "v"(p[2]), "v"(p[3]));
      asm("v_cvt_pk_bf16_f32 %0, %1, %2" : "=v"(y0) : "v"(p[4]), "v"(p[5]));
      asm("v_cvt_pk_bf16_f32 %0, %1, %2" : "=v"(y1) : "v"(p[6]), "v"(p[7]));
      asm("v_permlane32_swap_b32 %0, %1" : "+v"(x0), "+v"(y0));
      asm("v_permlane32_swap_b32 %0, %1" : "+v"(x1), "+v"(y1));
      union { uint u[4]; short8 s; } pa0;
      pa0.u[0] = x0; pa0.u[1] = x1; pa0.u[2] = y0; pa0.u[3] = y1;

      uint z0, z1, w0, w1;
      asm("v_cvt_pk_bf16_f32 %0, %1, %2" : "=v"(z0) : "v"(p[8]), "v"(p[9]));
      asm("v_cvt_pk_bf16_f32 %0, %1, %2" : "=v"(z1) : "v"(p[10]), "v"(p[11]));
      asm("v_cvt_pk_bf16_f32 %0, %1, %2" : "=v"(w0) : "v"(p[12]), "v"(p[13]));
      asm("v_cvt_pk_bf16_f32 %0, %1, %2" : "=v"(w1) : "v"(p[14]), "v"(p[15]));
      asm("v_permlane32_swap_b32 %0, %1" : "+v"(z0), "+v"(w0));
      asm("v_permlane32_swap_b32 %0, %1" : "+v"(z1), "+v"(w1));
      union { uint u[4]; short8 s; } pa1;
      pa1.u[0] = z0; pa1.u[1] = z1; pa1.u[2] = w0; pa1.u[3] = w1;

      short8 vf0 = *reinterpret_cast<const short8*>(Vc + vrow * VROW + jl * 32 + lg * 8);
      short8 vf1 = *reinterpret_cast<const short8*>(Vc + vrow * VROW + jl * 32 + 16 + lg * 8);

      accO = __builtin_amdgcn_mfma_f32_32x32x16_bf16(pa0.s, vf0, accO, 0, 0, 0);
      accO = __builtin_amdgcn_mfma_f32_32x32x16_bf16(pa1.s, vf1, accO, 0, 0, 0);
    }
    if (ch + 1 < NCH) {
      __syncthreads();
      const int nxt = (ch + 1) & 1;
#pragma unroll
      for (int u = 0; u < 8; ++u)
        Vs[nxt][(vhalf * 8 + u) * VROW + vj] = (ushort)vreg[u];
      if (ch + 2 < NCH) {
        vreg = *reinterpret_cast<const short8*>(
            Vg + (size_t)((ch + 2) * JC + vj) * DHEAD + vhalf * 8);
      }
      __syncthreads();
    }
  }

  const int h = wh & 3;
  const int w = (wh >> 2) & 7;
  const int b = (wh >> 5) & 3;
  const int e = wh >> 7;
  const size_t rowbase =
      (size_t)e * NROWS + (size_t)b * NSEQ + (size_t)w * WSZ + (size_t)qtile * 32;
  const int src = 16 + 32 * lg;

#pragma unroll
  for (int r = 0; r < 16; ++r) {
    float den = __shfl(accO[r], src);
    if (n31 < 16) {
      int i = (r & 3) + 8 * (r >> 2) + 4 * lg;
      float val = accO[r] * __builtin_amdgcn_rcpf(den);
      ao[(rowbase + i) * INNER + h * DHEAD + n31] = (ushort)pkbf(val, val);
    }
  }
}

// ---------------------------------------------------------------------------
// Kernel 3: out = (ao1 + ao2) @ Wout^T + 2*bout (bf16 ao in, fp32 math).
// ---------------------------------------------------------------------------
#define OSTR 76
__global__ __launch_bounds__(192) void out_proj(const ushort* __restrict__ ao_all,
                                                const float* __restrict__ Wout,
                                                const float* __restrict__ bout,
                                                float* __restrict__ out) {
  const int tid = threadIdx.x;
  const int row0 = blockIdx.x * 64;

  __shared__ float aos[64 * OSTR];

  const ushort* __restrict__ a1 = ao_all;
  const ushort* __restrict__ a2 = ao_all + (size_t)AO_PER;

  for (int idx = tid; idx < 64 * 8; idx += 192) {
    const int r = idx >> 3, c = idx & 7;
    const size_t g = (size_t)(row0 + r) * INNER + c * 8;
    short8 u = *reinterpret_cast<const short8*>(a1 + g);
    short8 v = *reinterpret_cast<const short8*>(a2 + g);
    float4 s0, s1;
    s0.x = bf2f((ushort)u[0]) + bf2f((ushort)v[0]);
    s0.y = bf2f((ushort)u[1]) + bf2f((ushort)v[1]);
    s0.z = bf2f((ushort)u[2]) + bf2f((ushort)v[2]);
    s0.w = bf2f((ushort)u[3]) + bf2f((ushort)v[3]);
    s1.x = bf2f((ushort)u[4]) + bf2f((ushort)v[4]);
    s1.y = bf2f((ushort)u[5]) + bf2f((ushort)v[5]);
    s1.z = bf2f((ushort)u[6]) + bf2f((ushort)v[6]);
    s1.w = bf2f((ushort)u[7]) + bf2f((ushort)v[7]);
    *reinterpret_cast<float4*>(aos + r * OSTR + c * 8) = s0;
    *reinterpret_cast<float4*>(aos + r * OSTR + c * 8 + 4) = s1;
  }

  const int j = tid % 48;
  const int rq = tid / 48;

  float wreg[INNER];
#pragma unroll
  for (int k4 = 0; k4 < 16; ++k4) {
    float4 wv4 = reinterpret_cast<const float4*>(Wout + (size_t)j * INNER)[k4];
    wreg[k4 * 4 + 0] = wv4.x; wreg[k4 * 4 + 1] = wv4.y;
    wreg[k4 * 4 + 2] = wv4.z; wreg[k4 * 4 + 3] = wv4.w;
  }
  const float bj = 2.0f * bout[j];

  __syncthreads();

  for (int r16 = 0; r16 < 16; ++r16) {
    const int r = rq * 16 + r16;
    float a0 = 0.f, a1v = 0.f, a2v = 0.f, a3 = 0.f;
#pragma unroll
    for (int kk = 0; kk < 16; ++kk) {
      const int k4 = (kk + rq * 4) & 15;
      float4 av = *reinterpret_cast<const float4*>(aos + r * OSTR + k4 * 4);
      a0 = fmaf(av.x, wreg[k4 * 4 + 0], a0);
      a1v = fmaf(av.y, wreg[k4 * 4 + 1], a1v);
      a2v = fmaf(av.z, wreg[k4 * 4 + 2], a2v);
      a3 = fmaf(av.w, wreg[k4 * 4 + 3], a3);
    }
    out[(size_t)(row0 + r) * CDIM + j] = (a0 + a1v) + (a2v + a3) + bj;
  }
}

// ---------------------------------------------------------------------------
extern "C" void kernel_launch(void* const* d_in, const int* in_sizes, int n_in,
                              void* d_out, int out_size, void* d_ws,
                              size_t ws_size, hipStream_t stream) {
  const float* x1 = (const float*)d_in[0];
  const float* x2 = (const float*)d_in[1];
  const float* Wqkv = (const float*)d_in[2];
  const float* Wout = (const float*)d_in[3];
  const float* bout = (const float*)d_in[4];
  float* out = (float*)d_out;
  ushort* wsq = (ushort*)d_ws;
  ushort* ao = wsq + QKV_TOTAL;          // bf16 region after bf16 QKV

  qkv_mfma<<<dim3(800), dim3(256), 0, stream>>>(x1, x2, Wqkv, wsq);
  attn_mfma<<<dim3(1280), dim3(320), 0, stream>>>(wsq, ao);
  out_proj<<<dim3(400), dim3(192), 0, stream>>>(ao, Wout, bout, out);
}

// Round 17
// 53.856 us; speedup vs baseline: 1.3182x; 1.2238x over previous
//
#include <hip/hip_runtime.h>
#include <cstddef>

typedef __attribute__((ext_vector_type(8))) short short8;
typedef __attribute__((ext_vector_type(16))) float f32x16;

#define NB 4
#define NSEQ 6400
#define CDIM 48
#define DHEAD 16
#define WSZ 800
#define NWIN 8
#define INNER 64
#define NROWS 25600
#define NWH 256                       // 2*NB*NWIN*NHEADS window-heads
#define SCHUNK (WSZ * DHEAD)          // 12800
#define CHUNK (3 * SCHUNK)            // 38400 bf16 per (e,b,w,h)
#define QKV_TOTAL (NWH * CHUNK)
#define AO_PER (NROWS * INNER)        // bf16 elements per input

static __device__ __forceinline__ uint pkbf(float a, float b) {
  uint r;
  asm("v_cvt_pk_bf16_f32 %0, %1, %2" : "=v"(r) : "v"(a), "v"(b));
  return r;
}
static __device__ __forceinline__ float bf2f(ushort u) {
  return __uint_as_float(((uint)u) << 16);
}

// ---------------------------------------------------------------------------
// Kernel 1: QKV projection via MFMA, C^T formulation (r16 champion, verbatim).
// ---------------------------------------------------------------------------
__global__ __launch_bounds__(256) void qkv_mfma(const float* __restrict__ x1,
                                                const float* __restrict__ x2,
                                                const float* __restrict__ Wqkv,
                                                ushort* __restrict__ wsq) {
  const int tid = threadIdx.x;
  const int lane = tid & 63;
  const int wv = tid >> 6;

  __shared__ __align__(16) ushort Wl[18 * 64 * 8];   // 18.4 KB, frag order
  __shared__ __align__(16) ushort Obuf[4][6 * 512];  // 6KB per wave

  for (int slot = tid; slot < 1152; slot += 256) {
    const int mtks = slot >> 6, l2 = slot & 63;
    const int mt = mtks / 3, ks = mtks % 3;
    const int o = mt * 32 + (l2 & 31);
    const int c0 = ks * 16 + (l2 >> 5) * 8;
    const float sc = ((o % CDIM) < DHEAD) ? 0.25f : 1.0f;   // fold attn scale
    const float4* p = reinterpret_cast<const float4*>(Wqkv + (size_t)o * CDIM + c0);
    float4 u = p[0], v = p[1];
    union { uint q[4]; short8 s; } t;
    t.q[0] = pkbf(u.x * sc, u.y * sc); t.q[1] = pkbf(u.z * sc, u.w * sc);
    t.q[2] = pkbf(v.x * sc, v.y * sc); t.q[3] = pkbf(v.z * sc, v.w * sc);
    *reinterpret_cast<short8*>(Wl + (size_t)slot * 8) = t.s;
  }
  __syncthreads();

  const int task = blockIdx.x * 4 + wv;   // [0,3200)
  const int batch = task >> 1;
  const int mh = task & 1;
  const int e = batch / 800;
  const int rb = (batch % 800) * 32;
  const float* __restrict__ x = e ? x2 : x1;

  const int rl = lane & 31;
  const int lg = lane >> 5;
  const int row = rb + rl;

  short8 bf[3];
#pragma unroll
  for (int ks = 0; ks < 3; ++ks) {
    const float4* p =
        reinterpret_cast<const float4*>(x + (size_t)row * CDIM + ks * 16 + lg * 8);
    float4 u = p[0], v = p[1];
    union { uint q[4]; short8 s; } t;
    t.q[0] = pkbf(u.x, u.y); t.q[1] = pkbf(u.z, u.w);
    t.q[2] = pkbf(v.x, v.y); t.q[3] = pkbf(v.z, v.w);
    bf[ks] = t.s;
  }

  const int b = rb / NSEQ;
  const int i0 = rb % NSEQ;
  const int wi = i0 / WSZ;
  const int iwb = i0 % WSZ;
  const int whb = ((e * NB + b) * NWIN + wi) * 4;

#pragma unroll
  for (int mt = mh * 3; mt < mh * 3 + 3; ++mt) {
    const int obase = mt * 32;
    short8 wf0 = *reinterpret_cast<const short8*>(Wl + ((mt * 3 + 0) * 64 + lane) * 8);
    short8 wf1 = *reinterpret_cast<const short8*>(Wl + ((mt * 3 + 1) * 64 + lane) * 8);
    short8 wf2 = *reinterpret_cast<const short8*>(Wl + ((mt * 3 + 2) * 64 + lane) * 8);

    f32x16 acc;
#pragma unroll
    for (int r = 0; r < 16; ++r) acc[r] = 0.f;
    acc = __builtin_amdgcn_mfma_f32_32x32x16_bf16(wf0, bf[0], acc, 0, 0, 0);
    acc = __builtin_amdgcn_mfma_f32_32x32x16_bf16(wf1, bf[1], acc, 0, 0, 0);
    acc = __builtin_amdgcn_mfma_f32_32x32x16_bf16(wf2, bf[2], acc, 0, 0, 0);

#pragma unroll
    for (int q = 0; q < 4; ++q) {
      const int op = obase + q * 8 + 4 * lg - mh * 96;   // 0..95
      const int g2 = op >> 4;
      const int d0 = op & 15;
      uint2 pk;
      pk.x = pkbf(acc[4 * q + 0], acc[4 * q + 1]);
      pk.y = pkbf(acc[4 * q + 2], acc[4 * q + 3]);
      *reinterpret_cast<uint2*>(&Obuf[wv][g2 * 512 + rl * 16 + d0]) = pk;
    }
  }

#pragma unroll
  for (int g2 = 0; g2 < 6; ++g2) {
    const int g = mh * 6 + g2;           // global 16-o group
    const int h = g / 3, s = g % 3;
    short8 val = *reinterpret_cast<const short8*>(&Obuf[wv][g2 * 512 + lane * 8]);
    *reinterpret_cast<short8*>(wsq + (size_t)(whb + h) * CHUNK + s * SCHUNK +
                               (size_t)iwb * DHEAD + lane * 8) = val;
  }
}

// ---------------------------------------------------------------------------
// Kernel 2: MFMA windowed attention — r16 champion, verbatim.  (V-frag reads
// stay AFTER the pack block: hoisting breaks codegen — r9/r10/r15.)
// ---------------------------------------------------------------------------
#define JC 160
#define NCH 5
#define VROW 168
#define VSL (17 * VROW)

__global__ __launch_bounds__(320) void attn_mfma(const ushort* __restrict__ wsq,
                                                 ushort* __restrict__ ao) {
  const int tid = threadIdx.x;
  const int lane = tid & 63;
  const int wv = tid >> 6;
  const int bid = blockIdx.x;
  const int wh = bid & (NWH - 1);
  const int sub = bid >> 8;
  const int qtile = sub * 5 + wv;        // 0..24

  const ushort* __restrict__ Qg = wsq + (size_t)wh * CHUNK;
  const ushort* __restrict__ Kg = Qg + SCHUNK;
  const ushort* __restrict__ Vg = Kg + SCHUNK;

  __shared__ __align__(16) ushort Vs[2][VSL];   // 11.4 KB total

  const int vj = tid % 160;
  const int vhalf = tid / 160;

  short8 vreg = *reinterpret_cast<const short8*>(Vg + (size_t)vj * DHEAD + vhalf * 8);

  if (tid < JC) {
    Vs[0][16 * VROW + tid] = 0x3F80;
    Vs[1][16 * VROW + tid] = 0x3F80;
  }

#pragma unroll
  for (int u = 0; u < 8; ++u)
    Vs[0][(vhalf * 8 + u) * VROW + vj] = (ushort)vreg[u];

  vreg = *reinterpret_cast<const short8*>(Vg + (size_t)(JC + vj) * DHEAD + vhalf * 8);

  short8 qf = *reinterpret_cast<const short8*>(
      Qg + (size_t)(qtile * 32 + (lane & 31)) * DHEAD + (lane >> 5) * 8);

  __syncthreads();

  f32x16 sinit;
#pragma unroll
  for (int r = 0; r < 16; ++r) sinit[r] = -8.0f;   // softmax shift via C-in
  f32x16 accO;
#pragma unroll
  for (int r = 0; r < 16; ++r) accO[r] = 0.f;

  const int n31 = lane & 31;
  const int lg = lane >> 5;
  const int vrow = (n31 <= 16) ? n31 : (n31 & 15);   // col 16 -> ones row
  const ushort* __restrict__ kfb = Kg + (size_t)n31 * DHEAD + lg * 8;

  for (int ch = 0; ch < NCH; ++ch) {
    const ushort* __restrict__ Vc = Vs[ch & 1];
#pragma unroll
    for (int jl = 0; jl < 5; ++jl) {
      short8 kf = *reinterpret_cast<const short8*>(
          kfb + (size_t)(ch * JC + jl * 32) * DHEAD);
      f32x16 st = __builtin_amdgcn_mfma_f32_32x32x16_bf16(kf, qf, sinit, 0, 0, 0);

      float p[16];
#pragma unroll
      for (int r = 0; r < 16; ++r) p[r] = __expf(st[r]);   // exp(s-8)

      uint x0, x1, y0, y1;
      asm("v_cvt_pk_bf16_f32 %0, %1, %2" : "=v"(x0) : "v"(p[0]), "v"(p[1]));
      asm("v_cvt_pk_bf16_f32 %0, %1, %2" : "=v"(x1) : "v"(p[2]), "v"(p[3]));
      asm("v_cvt_pk_bf16_f32 %0, %1, %2" : "=v"(y0) : "v"(p[4]), "v"(p[5]));
      asm("v_cvt_pk_bf16_f32 %0, %1, %2" : "=v"(y1) : "v"(p[6]), "v"(p[7]));
      asm("v_permlane32_swap_b32 %0, %1" : "+v"(x0), "+v"(y0));
      asm("v_permlane32_swap_b32 %0, %1" : "+v"(x1), "+v"(y1));
      union { uint u[4]; short8 s; } pa0;
      pa0.u[0] = x0; pa0.u[1] = x1; pa0.u[2] = y0; pa0.u[3] = y1;

      uint z0, z1, w0, w1;
      asm("v_cvt_pk_bf16_f32 %0, %1, %2" : "=v"(z0) : "v"(p[8]), "v"(p[9]));
      asm("v_cvt_pk_bf16_f32 %0, %1, %2" : "=v"(z1) : "v"(p[10]), "v"(p[11]));
      asm("v_cvt_pk_bf16_f32 %0, %1, %2" : "=v"(w0) : "v"(p[12]), "v"(p[13]));
      asm("v_cvt_pk_bf16_f32 %0, %1, %2" : "=v"(w1) : "v"(p[14]), "v"(p[15]));
      asm("v_permlane32_swap_b32 %0, %1" : "+v"(z0), "+v"(w0));
      asm("v_permlane32_swap_b32 %0, %1" : "+v"(z1), "+v"(w1));
      union { uint u[4]; short8 s; } pa1;
      pa1.u[0] = z0; pa1.u[1] = z1; pa1.u[2] = w0; pa1.u[3] = w1;

      short8 vf0 = *reinterpret_cast<const short8*>(Vc + vrow * VROW + jl * 32 + lg * 8);
      short8 vf1 = *reinterpret_cast<const short8*>(Vc + vrow * VROW + jl * 32 + 16 + lg * 8);

      accO = __builtin_amdgcn_mfma_f32_32x32x16_bf16(pa0.s, vf0, accO, 0, 0, 0);
      accO = __builtin_amdgcn_mfma_f32_32x32x16_bf16(pa1.s, vf1, accO, 0, 0, 0);
    }
    if (ch + 1 < NCH) {
      __syncthreads();
      const int nxt = (ch + 1) & 1;
#pragma unroll
      for (int u = 0; u < 8; ++u)
        Vs[nxt][(vhalf * 8 + u) * VROW + vj] = (ushort)vreg[u];
      if (ch + 2 < NCH) {
        vreg = *reinterpret_cast<const short8*>(
            Vg + (size_t)((ch + 2) * JC + vj) * DHEAD + vhalf * 8);
      }
      __syncthreads();
    }
  }

  const int h = wh & 3;
  const int w = (wh >> 2) & 7;
  const int b = (wh >> 5) & 3;
  const int e = wh >> 7;
  const size_t rowbase =
      (size_t)e * NROWS + (size_t)b * NSEQ + (size_t)w * WSZ + (size_t)qtile * 32;
  const int src = 16 + 32 * lg;

#pragma unroll
  for (int r = 0; r < 16; ++r) {
    float den = __shfl(accO[r], src);
    if (n31 < 16) {
      int i = (r & 3) + 8 * (r >> 2) + 4 * lg;
      float val = accO[r] * __builtin_amdgcn_rcpf(den);
      ao[(rowbase + i) * INNER + h * DHEAD + n31] = (ushort)pkbf(val, val);
    }
  }
}

// ---------------------------------------------------------------------------
// Kernel 3: out = (ao1 + ao2) @ Wout^T + 2*bout via MFMA (qkv_mfma pattern).
// C^T: D[j][row] = sum_c Wout[j][c]*ao[row][c].  A-frag = Wout rows (LDS,
// bf16, row-47-clamped for the 48..63 tail — garbage D-rows not stored);
// B-frags = ao rows (already bf16, contiguous).  ao1+ao2 accumulated
// EXACTLY in the fp32 MFMA accumulator (two MFMAs per kstep, same C).
// Bias folded at Obuf write; 6 coalesced 1KB float4 stores per wave.
// 200 blocks x 256 threads; wave = 32 rows x 48 outputs.
// ---------------------------------------------------------------------------
__global__ __launch_bounds__(256) void out_mfma(const ushort* __restrict__ ao_all,
                                                const float* __restrict__ Wout,
                                                const float* __restrict__ bout,
                                                float* __restrict__ out) {
  const int tid = threadIdx.x;
  const int lane = tid & 63;
  const int wv = tid >> 6;

  __shared__ __align__(16) ushort Wlo[8 * 64 * 8];   // 8 KB: (mt*4+ks)*64+l2
  __shared__ __align__(16) float Obuf[4][32 * 48];   // 24 KB, wave-private

  for (int slot = tid; slot < 512; slot += 256) {
    const int mtks = slot >> 6, l2 = slot & 63;
    const int mt = mtks >> 2, ks = mtks & 3;
    int o = mt * 32 + (l2 & 31);
    if (o > 47) o = 47;                  // clamp: rows 48..63 unused in D
    const int c0 = ks * 16 + (l2 >> 5) * 8;
    const float4* p = reinterpret_cast<const float4*>(Wout + (size_t)o * INNER + c0);
    float4 u = p[0], v = p[1];
    union { uint q[4]; short8 s; } t;
    t.q[0] = pkbf(u.x, u.y); t.q[1] = pkbf(u.z, u.w);
    t.q[2] = pkbf(v.x, v.y); t.q[3] = pkbf(v.z, v.w);
    *reinterpret_cast<short8*>(Wlo + (size_t)slot * 8) = t.s;
  }
  __syncthreads();

  const int rb = (blockIdx.x * 4 + wv) * 32;   // 800 wave-tasks, rows [rb,rb+32)
  const int rl = lane & 31;
  const int lg = lane >> 5;

  const ushort* __restrict__ a1 = ao_all;
  const ushort* __restrict__ a2 = ao_all + (size_t)AO_PER;

  short8 b1[4], b2[4];
#pragma unroll
  for (int ks = 0; ks < 4; ++ks) {
    b1[ks] = *reinterpret_cast<const short8*>(
        a1 + (size_t)(rb + rl) * INNER + ks * 16 + lg * 8);
    b2[ks] = *reinterpret_cast<const short8*>(
        a2 + (size_t)(rb + rl) * INNER + ks * 16 + lg * 8);
  }

#pragma unroll
  for (int mt = 0; mt < 2; ++mt) {
    f32x16 acc;
#pragma unroll
    for (int r = 0; r < 16; ++r) acc[r] = 0.f;
#pragma unroll
    for (int ks = 0; ks < 4; ++ks) {
      short8 wf = *reinterpret_cast<const short8*>(
          Wlo + ((size_t)(mt * 4 + ks) * 64 + lane) * 8);
      acc = __builtin_amdgcn_mfma_f32_32x32x16_bf16(wf, b1[ks], acc, 0, 0, 0);
      acc = __builtin_amdgcn_mfma_f32_32x32x16_bf16(wf, b2[ks], acc, 0, 0, 0);
    }
    // D: o' = mt*32 + q*8 + 4*lg + k (k=0..3), row' = rb + (lane&31)
#pragma unroll
    for (int q = 0; q < 4; ++q) {
      const int op = mt * 32 + q * 8 + 4 * lg;
      if (op < CDIM) {
        float4 bb = *reinterpret_cast<const float4*>(bout + op);
        float4 val;
        val.x = acc[4 * q + 0] + 2.0f * bb.x;
        val.y = acc[4 * q + 1] + 2.0f * bb.y;
        val.z = acc[4 * q + 2] + 2.0f * bb.z;
        val.w = acc[4 * q + 3] + 2.0f * bb.w;
        *reinterpret_cast<float4*>(&Obuf[wv][rl * CDIM + op]) = val;
      }
    }
  }

  // coalesced store: 32 rows x 48 floats = 1536 contiguous at out + rb*48
#pragma unroll
  for (int it = 0; it < 6; ++it) {
    float4 v = *reinterpret_cast<const float4*>(&Obuf[wv][it * 256 + lane * 4]);
    *reinterpret_cast<float4*>(out + (size_t)rb * CDIM + it * 256 + lane * 4) = v;
  }
}

// ---------------------------------------------------------------------------
extern "C" void kernel_launch(void* const* d_in, const int* in_sizes, int n_in,
                              void* d_out, int out_size, void* d_ws,
                              size_t ws_size, hipStream_t stream) {
  const float* x1 = (const float*)d_in[0];
  const float* x2 = (const float*)d_in[1];
  const float* Wqkv = (const float*)d_in[2];
  const float* Wout = (const float*)d_in[3];
  const float* bout = (const float*)d_in[4];
  float* out = (float*)d_out;
  ushort* wsq = (ushort*)d_ws;
  ushort* ao = wsq + QKV_TOTAL;          // bf16 region after bf16 QKV

  qkv_mfma<<<dim3(800), dim3(256), 0, stream>>>(x1, x2, Wqkv, wsq);
  attn_mfma<<<dim3(1280), dim3(320), 0, stream>>>(wsq, ao);
  out_mfma<<<dim3(200), dim3(256), 0, stream>>>(ao, Wout, bout, out);
}